// Round 7
// baseline (521.296 us; speedup 1.0000x reference)
//
#include <hip/hip_runtime.h>
#include <hip/hip_bf16.h>
#include <stdint.h>

typedef __attribute__((ext_vector_type(4))) float f32x4;
typedef __attribute__((ext_vector_type(8))) short bf16x8;
typedef __attribute__((ext_vector_type(4))) short s16x4;

__device__ __forceinline__ float b2f(short s) {
    union { uint32_t u; float f; } v; v.u = ((uint32_t)(uint16_t)s) << 16; return v.f;
}
__device__ __forceinline__ short f2b(float f) {
    union { float f; uint32_t u; } v; v.f = f;
    uint32_t r = v.u + 0x7FFF + ((v.u >> 16) & 1);   // RNE
    return (short)(r >> 16);
}
__device__ __forceinline__ f32x4 zero4() { f32x4 z = {0.f, 0.f, 0.f, 0.f}; return z; }

__device__ __forceinline__ void async16(const void* g, void* l) {
    __builtin_amdgcn_global_load_lds(
        (const __attribute__((address_space(1))) void*)g,
        (__attribute__((address_space(3))) void*)l, 16, 0, 0);
}

// ---------------------------------------------------------------------------
// fp32 -> bf16 conversion pre-pass. Grid = 12288 blocks:
//   [0,8192)     : x  (8192 rows x 1024)
//   [8192,12288) : W_q/W_k/W_v/W_o (1024 blocks of 1024 each)
// ---------------------------------------------------------------------------
__global__ __launch_bounds__(256)
void cvt5(const float* __restrict__ x,
          const float* __restrict__ wq, const float* __restrict__ wk,
          const float* __restrict__ wv, const float* __restrict__ wo,
          short* __restrict__ xb, short* __restrict__ wqb, short* __restrict__ wkb,
          short* __restrict__ wvb, short* __restrict__ wob)
{
    const int b = blockIdx.x;
    const float* src; short* dst; size_t off;
    if (b < 8192) { src = x; dst = xb; off = (size_t)b * 1024; }
    else {
        const int wsel = (b - 8192) >> 10;
        off = (size_t)((b - 8192) & 1023) * 1024;
        switch (wsel) {
            case 0: src = wq; dst = wqb; break;
            case 1: src = wk; dst = wkb; break;
            case 2: src = wv; dst = wvb; break;
            default: src = wo; dst = wob; break;
        }
    }
    const int t = threadIdx.x;
    const float4 v = *(const float4*)(src + off + t * 4);
    s16x4 o;
    o[0] = f2b(v.x); o[1] = f2b(v.y); o[2] = f2b(v.z); o[3] = f2b(v.w);
    *(s16x4*)(dst + off + t * 4) = o;
}

// ---------------------------------------------------------------------------
// GEMM: C[M,N] = A[M,K] * B[N,K]^T + bias (+ optional fp32 residual).
// A,B bf16 (ws); bias/resid fp32. OUTF32=false -> bf16 C (ws tensors);
// OUTF32=true  -> fp32 C (d_out) + residual.
// 128x128 tile, BK=32, 4 waves (2x2 of 64x64), mfma_f32_16x16x32_bf16.
// Cross-validated against a scalar VALU reference in rounds 3-6.
// ---------------------------------------------------------------------------
template <bool OUTF32, bool RESID>
__global__ __launch_bounds__(256)
void gemm_bt(const short* __restrict__ A, const short* __restrict__ Bw,
             const float* __restrict__ bias, const float* __restrict__ resid,
             void* __restrict__ Cv, int M, int N, int K)
{
    __shared__ short lsA[128 * 32];
    __shared__ short lsB[128 * 32];
    const int t = threadIdx.x;
    const int wave = t >> 6, lane = t & 63;
    const int wr = wave >> 1, wc = wave & 1;
    const int lr = lane & 15, kg = lane >> 4;
    const int m0 = blockIdx.y * 128;
    const int n0 = blockIdx.x * 128;

    f32x4 acc[4][4];
#pragma unroll
    for (int m = 0; m < 4; ++m)
#pragma unroll
        for (int n = 0; n < 4; ++n) acc[m][n] = zero4();

    const short* Ab = A + (size_t)m0 * K;
    const short* Bb = Bw + (size_t)n0 * K;
    const int r0 = t >> 2;            // 0..63
    const int c0 = (t & 3) * 8;       // 0,8,16,24

    for (int k0 = 0; k0 < K; k0 += 32) {
        __syncthreads();
        async16(Ab + (size_t)r0 * K + k0 + c0,        &lsA[t * 8]);
        async16(Ab + (size_t)(r0 + 64) * K + k0 + c0, &lsA[t * 8 + 2048]);
        async16(Bb + (size_t)r0 * K + k0 + c0,        &lsB[t * 8]);
        async16(Bb + (size_t)(r0 + 64) * K + k0 + c0, &lsB[t * 8 + 2048]);
        __syncthreads();

        bf16x8 aF[4], bF[4];
#pragma unroll
        for (int m = 0; m < 4; ++m)
            aF[m] = *(const bf16x8*)&lsA[(wr * 64 + m * 16 + lr) * 32 + kg * 8];
#pragma unroll
        for (int n = 0; n < 4; ++n)
            bF[n] = *(const bf16x8*)&lsB[(wc * 64 + n * 16 + lr) * 32 + kg * 8];
#pragma unroll
        for (int m = 0; m < 4; ++m)
#pragma unroll
            for (int n = 0; n < 4; ++n)
                acc[m][n] = __builtin_amdgcn_mfma_f32_16x16x32_bf16(aF[m], bF[n], acc[m][n], 0, 0, 0);
    }

#pragma unroll
    for (int n = 0; n < 4; ++n) {
        const int col = n0 + wc * 64 + n * 16 + lr;
        const float bv = bias[col];
#pragma unroll
        for (int m = 0; m < 4; ++m) {
            const int rowb = m0 + wr * 64 + m * 16 + kg * 4;
#pragma unroll
            for (int r = 0; r < 4; ++r) {
                const size_t idx = (size_t)(rowb + r) * N + col;
                float v = acc[m][n][r] + bv;
                if (RESID) v += resid[idx];
                if (OUTF32) ((float*)Cv)[idx] = v;
                else        ((short*)Cv)[idx] = f2b(v);
            }
        }
    }
}

// ---------------------------------------------------------------------------
// MFMA flash attention. Block = 4 waves; each wave owns 32 q-rows (128-row
// Q tile). KVBLK=32 staged in LDS. Online softmax per 16-lane group.
// Q/K/V/ctx are [B*S, 1024] bf16. Cross-validated vs scalar VALU attention.
// ---------------------------------------------------------------------------
__global__ __launch_bounds__(256)
void attn_fwd(const short* __restrict__ Q, const short* __restrict__ K,
              const short* __restrict__ V, short* __restrict__ ctx)
{
    __shared__ short lsK[32 * 64];
    __shared__ short lsV[32 * 64];
    __shared__ short lsP[4][32 * 32];

    const int t = threadIdx.x, w = t >> 6, lane = t & 63;
    const int lr = lane & 15, kg = lane >> 4;
    const int bh = blockIdx.y;
    const size_t base = (size_t)(bh >> 4) * 2048 * 1024 + (size_t)(bh & 15) * 64;
    const short* Qg = Q + base;
    const short* Kg = K + base;
    const short* Vg = V + base;
    short* Og = ctx + base;
    const int q0 = blockIdx.x * 128 + w * 32;

    bf16x8 qA[2][2];
#pragma unroll
    for (int m = 0; m < 2; ++m)
#pragma unroll
        for (int ks = 0; ks < 2; ++ks)
            qA[m][ks] = *(const bf16x8*)(Qg + (size_t)(q0 + m * 16 + lr) * 1024 + ks * 32 + kg * 8);

    f32x4 o[2][4];
    float mx[2][4], lsum[2][4];
#pragma unroll
    for (int m = 0; m < 2; ++m) {
#pragma unroll
        for (int n = 0; n < 4; ++n) o[m][n] = zero4();
#pragma unroll
        for (int r = 0; r < 4; ++r) { mx[m][r] = -1e30f; lsum[m][r] = 0.f; }
    }

    const int vr = t >> 3;          // 0..31
    const int vc = (t & 7) * 8;     // 0..56

    for (int kv0 = 0; kv0 < 2048; kv0 += 32) {
        __syncthreads();
        async16(Kg + (size_t)(kv0 + vr) * 1024 + vc, &lsK[t * 8]);
        async16(Vg + (size_t)(kv0 + vr) * 1024 + vc, &lsV[t * 8]);
        __syncthreads();

        bf16x8 kB[2][2];
#pragma unroll
        for (int cb = 0; cb < 2; ++cb)
#pragma unroll
            for (int ks = 0; ks < 2; ++ks)
                kB[cb][ks] = *(const bf16x8*)&lsK[(cb * 16 + lr) * 64 + ks * 32 + kg * 8];
        f32x4 s[2][2];
#pragma unroll
        for (int m = 0; m < 2; ++m)
#pragma unroll
            for (int cb = 0; cb < 2; ++cb) {
                f32x4 a = __builtin_amdgcn_mfma_f32_16x16x32_bf16(qA[m][0], kB[cb][0], zero4(), 0, 0, 0);
                s[m][cb] = __builtin_amdgcn_mfma_f32_16x16x32_bf16(qA[m][1], kB[cb][1], a, 0, 0, 0);
            }

#pragma unroll
        for (int m = 0; m < 2; ++m) {
#pragma unroll
            for (int r = 0; r < 4; ++r) {
                float a = s[m][0][r] * 0.125f;
                float b = s[m][1][r] * 0.125f;
                float tmax = fmaxf(a, b);
                tmax = fmaxf(tmax, __shfl_xor(tmax, 1));
                tmax = fmaxf(tmax, __shfl_xor(tmax, 2));
                tmax = fmaxf(tmax, __shfl_xor(tmax, 4));
                tmax = fmaxf(tmax, __shfl_xor(tmax, 8));
                const float mnew = fmaxf(mx[m][r], tmax);
                const float corr = __expf(mx[m][r] - mnew);
                const float p0 = __expf(a - mnew);
                const float p1 = __expf(b - mnew);
                float tsum = p0 + p1;
                tsum += __shfl_xor(tsum, 1);
                tsum += __shfl_xor(tsum, 2);
                tsum += __shfl_xor(tsum, 4);
                tsum += __shfl_xor(tsum, 8);
                lsum[m][r] = lsum[m][r] * corr + tsum;
                mx[m][r] = mnew;
#pragma unroll
                for (int n = 0; n < 4; ++n) o[m][n][r] *= corr;
                const int prow = m * 16 + kg * 4 + r;
                lsP[w][prow * 32 + lr] = f2b(p0);
                lsP[w][prow * 32 + 16 + lr] = f2b(p1);
            }
        }

        bf16x8 pA[2];
#pragma unroll
        for (int m = 0; m < 2; ++m)
            pA[m] = *(const bf16x8*)&lsP[w][(m * 16 + lr) * 32 + kg * 8];
#pragma unroll
        for (int n = 0; n < 4; ++n) {
            bf16x8 vB;
#pragma unroll
            for (int j = 0; j < 8; ++j) vB[j] = lsV[(kg * 8 + j) * 64 + n * 16 + lr];
#pragma unroll
            for (int m = 0; m < 2; ++m)
                o[m][n] = __builtin_amdgcn_mfma_f32_16x16x32_bf16(pA[m], vB, o[m][n], 0, 0, 0);
        }
    }

#pragma unroll
    for (int m = 0; m < 2; ++m)
#pragma unroll
        for (int n = 0; n < 4; ++n)
#pragma unroll
            for (int r = 0; r < 4; ++r) {
                const int row = q0 + m * 16 + kg * 4 + r;
                Og[(size_t)row * 1024 + n * 16 + lr] = f2b(o[m][n][r] / lsum[m][r]);
            }
}

// ---------------------------------------------------------------------------
// In-place rowwise LayerNorm on d_out (fp32!), row = 1024, 256 threads.
// Single-barrier: sum & sum-of-squares together (var = E[x^2]-mu^2, clamped).
// ---------------------------------------------------------------------------
__global__ __launch_bounds__(256)
void ln_inplace(float* __restrict__ io, const float* __restrict__ gamma,
                const float* __restrict__ beta)
{
    __shared__ float redS[4];
    __shared__ float redQ[4];
    const int t = threadIdx.x, wave = t >> 6, lane = t & 63;
    const size_t rb = (size_t)blockIdx.x * 1024;

    float4 v4 = *(const float4*)&io[rb + t * 4];
    float v[4] = {v4.x, v4.y, v4.z, v4.w};

    float s = 0.f, sq = 0.f;
#pragma unroll
    for (int j = 0; j < 4; ++j) { s += v[j]; sq += v[j] * v[j]; }
#pragma unroll
    for (int off = 32; off; off >>= 1) {
        s  += __shfl_xor(s, off);
        sq += __shfl_xor(sq, off);
    }
    if (lane == 0) { redS[wave] = s; redQ[wave] = sq; }
    __syncthreads();
    const float mean = (redS[0] + redS[1] + redS[2] + redS[3]) * (1.0f / 1024.0f);
    const float ex2  = (redQ[0] + redQ[1] + redQ[2] + redQ[3]) * (1.0f / 1024.0f);
    const float var  = fmaxf(ex2 - mean * mean, 0.f);
    const float inv  = rsqrtf(var + 1e-5f);

    float4 o4;
    o4.x = (v[0] - mean) * inv * gamma[t * 4 + 0] + beta[t * 4 + 0];
    o4.y = (v[1] - mean) * inv * gamma[t * 4 + 1] + beta[t * 4 + 1];
    o4.z = (v[2] - mean) * inv * gamma[t * 4 + 2] + beta[t * 4 + 2];
    o4.w = (v[3] - mean) * inv * gamma[t * 4 + 3] + beta[t * 4 + 3];
    *(float4*)&io[rb + t * 4] = o4;
}

// ---------------------------------------------------------------------------
extern "C" void kernel_launch(void* const* d_in, const int* in_sizes, int n_in,
                              void* d_out, int out_size, void* d_ws, size_t ws_size,
                              hipStream_t stream)
{
    const float* x  = (const float*)d_in[0];
    const float* Wq = (const float*)d_in[1];
    const float* bq = (const float*)d_in[2];
    const float* Wk = (const float*)d_in[3];
    const float* bk = (const float*)d_in[4];
    const float* Wv = (const float*)d_in[5];
    const float* bv = (const float*)d_in[6];
    const float* Wo = (const float*)d_in[7];
    const float* bo = (const float*)d_in[8];
    const float* gamma = (const float*)d_in[9];
    const float* beta  = (const float*)d_in[10];

    const size_t NX = (size_t)8192 * 1024;   // x / Q / K / V / ctx elements
    const size_t NW = (size_t)1024 * 1024;   // weight elements

    short* xb  = (short*)d_ws;
    short* Wqb = xb + NX;
    short* Wkb = Wqb + NW;
    short* Wvb = Wkb + NW;
    short* Wob = Wvb + NW;
    short* Qw  = Wob + NW;
    short* Kw  = Qw + NX;
    short* Vw  = Kw + NX;
    short* Cw  = Vw + NX;
    float* out = (float*)d_out;              // fp32 output!

    dim3 blk(256);
    cvt5<<<dim3(12288), blk, 0, stream>>>(x, Wq, Wk, Wv, Wo, xb, Wqb, Wkb, Wvb, Wob);
    gemm_bt<false, false><<<dim3(8, 64), blk, 0, stream>>>(xb, Wqb, bq, nullptr, Qw, 8192, 1024, 1024);
    gemm_bt<false, false><<<dim3(8, 64), blk, 0, stream>>>(xb, Wkb, bk, nullptr, Kw, 8192, 1024, 1024);
    gemm_bt<false, false><<<dim3(8, 64), blk, 0, stream>>>(xb, Wvb, bv, nullptr, Vw, 8192, 1024, 1024);
    attn_fwd<<<dim3(16, 64), blk, 0, stream>>>(Qw, Kw, Vw, Cw);
    gemm_bt<true,  true ><<<dim3(8, 64), blk, 0, stream>>>(Cw, Wob, bo, x, out, 8192, 1024, 1024);
    ln_inplace<<<dim3(8192), blk, 0, stream>>>(out, gamma, beta);
}

// Round 8
// 297.954 us; speedup vs baseline: 1.7496x; 1.7496x over previous
//
#include <hip/hip_runtime.h>
#include <hip/hip_bf16.h>
#include <stdint.h>

typedef __attribute__((ext_vector_type(4))) float f32x4;
typedef __attribute__((ext_vector_type(8))) short bf16x8;
typedef __attribute__((ext_vector_type(4))) short bf16x4;
typedef __attribute__((ext_vector_type(4))) short s16x4;

__device__ __forceinline__ float b2f(short s) {
    union { uint32_t u; float f; } v; v.u = ((uint32_t)(uint16_t)s) << 16; return v.f;
}
__device__ __forceinline__ short f2b(float f) {
    union { float f; uint32_t u; } v; v.f = f;
    uint32_t r = v.u + 0x7FFF + ((v.u >> 16) & 1);   // RNE
    return (short)(r >> 16);
}
__device__ __forceinline__ f32x4 zero4() { f32x4 z = {0.f, 0.f, 0.f, 0.f}; return z; }

__device__ __forceinline__ void async16(const void* g, void* l) {
    __builtin_amdgcn_global_load_lds(
        (const __attribute__((address_space(1))) void*)g,
        (__attribute__((address_space(3))) void*)l, 16, 0, 0);
}
__device__ __forceinline__ uint32_t lds_addr(const void* p) {
    return (uint32_t)(uintptr_t)(const __attribute__((address_space(3))) void*)p;
}

// ---------------------------------------------------------------------------
// fp32 -> bf16 conversion pre-pass (unchanged, verified round 7).
// ---------------------------------------------------------------------------
__global__ __launch_bounds__(256)
void cvt5(const float* __restrict__ x,
          const float* __restrict__ wq, const float* __restrict__ wk,
          const float* __restrict__ wv, const float* __restrict__ wo,
          short* __restrict__ xb, short* __restrict__ wqb, short* __restrict__ wkb,
          short* __restrict__ wvb, short* __restrict__ wob)
{
    const int b = blockIdx.x;
    const float* src; short* dst; size_t off;
    if (b < 8192) { src = x; dst = xb; off = (size_t)b * 1024; }
    else {
        const int wsel = (b - 8192) >> 10;
        off = (size_t)((b - 8192) & 1023) * 1024;
        switch (wsel) {
            case 0: src = wq; dst = wqb; break;
            case 1: src = wk; dst = wkb; break;
            case 2: src = wv; dst = wvb; break;
            default: src = wo; dst = wob; break;
        }
    }
    const int t = threadIdx.x;
    const float4 v = *(const float4*)(src + off + t * 4);
    s16x4 o;
    o[0] = f2b(v.x); o[1] = f2b(v.y); o[2] = f2b(v.z); o[3] = f2b(v.w);
    *(s16x4*)(dst + off + t * 4) = o;
}

// ---------------------------------------------------------------------------
// GEMM (unchanged, verified round 7).
// ---------------------------------------------------------------------------
template <bool OUTF32, bool RESID>
__global__ __launch_bounds__(256)
void gemm_bt(const short* __restrict__ A, const short* __restrict__ Bw,
             const float* __restrict__ bias, const float* __restrict__ resid,
             void* __restrict__ Cv, int M, int N, int K)
{
    __shared__ short lsA[128 * 32];
    __shared__ short lsB[128 * 32];
    const int t = threadIdx.x;
    const int wave = t >> 6, lane = t & 63;
    const int wr = wave >> 1, wc = wave & 1;
    const int lr = lane & 15, kg = lane >> 4;
    const int m0 = blockIdx.y * 128;
    const int n0 = blockIdx.x * 128;

    f32x4 acc[4][4];
#pragma unroll
    for (int m = 0; m < 4; ++m)
#pragma unroll
        for (int n = 0; n < 4; ++n) acc[m][n] = zero4();

    const short* Ab = A + (size_t)m0 * K;
    const short* Bb = Bw + (size_t)n0 * K;
    const int r0 = t >> 2;
    const int c0 = (t & 3) * 8;

    for (int k0 = 0; k0 < K; k0 += 32) {
        __syncthreads();
        async16(Ab + (size_t)r0 * K + k0 + c0,        &lsA[t * 8]);
        async16(Ab + (size_t)(r0 + 64) * K + k0 + c0, &lsA[t * 8 + 2048]);
        async16(Bb + (size_t)r0 * K + k0 + c0,        &lsB[t * 8]);
        async16(Bb + (size_t)(r0 + 64) * K + k0 + c0, &lsB[t * 8 + 2048]);
        __syncthreads();

        bf16x8 aF[4], bF[4];
#pragma unroll
        for (int m = 0; m < 4; ++m)
            aF[m] = *(const bf16x8*)&lsA[(wr * 64 + m * 16 + lr) * 32 + kg * 8];
#pragma unroll
        for (int n = 0; n < 4; ++n)
            bF[n] = *(const bf16x8*)&lsB[(wc * 64 + n * 16 + lr) * 32 + kg * 8];
#pragma unroll
        for (int m = 0; m < 4; ++m)
#pragma unroll
            for (int n = 0; n < 4; ++n)
                acc[m][n] = __builtin_amdgcn_mfma_f32_16x16x32_bf16(aF[m], bF[n], acc[m][n], 0, 0, 0);
    }

#pragma unroll
    for (int n = 0; n < 4; ++n) {
        const int col = n0 + wc * 64 + n * 16 + lr;
        const float bv = bias[col];
#pragma unroll
        for (int m = 0; m < 4; ++m) {
            const int rowb = m0 + wr * 64 + m * 16 + kg * 4;
#pragma unroll
            for (int r = 0; r < 4; ++r) {
                const size_t idx = (size_t)(rowb + r) * N + col;
                float v = acc[m][n][r] + bv;
                if (RESID) v += resid[idx];
                if (OUTF32) ((float*)Cv)[idx] = v;
                else        ((short*)Cv)[idx] = f2b(v);
            }
        }
    }
}

// ---------------------------------------------------------------------------
// MFMA flash attention, v2.
//  - swapped QK^T: s = mfma(K_frag, Q_frag) so lane owns q-row (lane&15):
//    softmax reduce = in-lane fmax + 2 shfl_xor (16,32); corr broadcast 4 shfl.
//  - KVBLK=64, double-buffered K/V staging, ONE barrier per tile.
//  - K staged with XOR-pre-swizzled global source (linear LDS dest);
//    reads use chunk' = chunk ^ (row&7)  -> b128 reads at bank floor.
//  - V staged into subtiled planes [d>>4][kv][d&15]; PV B-fragments via
//    ds_read_b64_tr_b16 (stride-32B HW transpose read).
//  - P packed bf16 pairs into padded lsP[32][72] (per wave; same-wave reuse).
// Grid: (64 bh, 16 q-tiles) -> consecutive blocks share XCD per bh (L2 reuse).
// ---------------------------------------------------------------------------
__global__ __launch_bounds__(256)
void attn_fwd(const short* __restrict__ Q, const short* __restrict__ K,
              const short* __restrict__ V, short* __restrict__ ctx)
{
    __shared__ short lsK[2][64 * 64];
    __shared__ short lsV[2][64 * 64];
    __shared__ short lsP[4][32 * 72];

    const int t = threadIdx.x, w = t >> 6, lane = t & 63;
    const int lr = lane & 15, kg = lane >> 4;
    const int bh = blockIdx.x;                 // bh-major for XCD/L2 locality
    const size_t base = (size_t)(bh >> 4) * 2048 * 1024 + (size_t)(bh & 15) * 64;
    const short* Qg = Q + base;
    const short* Kg = K + base;
    const short* Vg = V + base;
    short* Og = ctx + base;
    const int q0 = blockIdx.y * 128 + w * 32;

    // Q fragments (B operand of swapped QK^T), rows m*16+lr
    bf16x8 qB[2][2];
#pragma unroll
    for (int m = 0; m < 2; ++m)
#pragma unroll
        for (int ks = 0; ks < 2; ++ks)
            qB[m][ks] = *(const bf16x8*)(Qg + (size_t)(q0 + m * 16 + lr) * 1024 + ks * 32 + kg * 8);

    // staging geometry (256 threads, 4 async16 each per 64-row tile)
    const int rK  = t >> 3;                          // K row 0..31 (and +32)
    const int cK  = (((t & 7) ^ (rK & 7))) * 8;      // XOR-pre-swizzled source chunk
    const int kvV = (t & 127) >> 1;                  // V row 0..63
    const int dV0 = ((t >> 7) << 4) + (t & 1) * 8;   // V d-offset (plane t>>7)
    const int dV1 = dV0 + 32;                        // plane +2

    f32x4 o[2][4];
#pragma unroll
    for (int m = 0; m < 2; ++m)
#pragma unroll
        for (int n = 0; n < 4; ++n) o[m][n] = zero4();
    float mx[2] = {-1e30f, -1e30f};
    float lsum[2] = {0.f, 0.f};

    // prologue stage -> buf 0
    async16(Kg + (size_t)rK * 1024 + cK,        &lsK[0][t * 8]);
    async16(Kg + (size_t)(32 + rK) * 1024 + cK, &lsK[0][t * 8 + 2048]);
    async16(Vg + (size_t)kvV * 1024 + dV0,      &lsV[0][t * 8]);
    async16(Vg + (size_t)kvV * 1024 + dV1,      &lsV[0][t * 8 + 2048]);

    int buf = 0;
    for (int it = 0; it < 32; ++it) {
        __syncthreads();   // drains vmcnt -> stage(it) landed; syncs waves
        if (it + 1 < 32) {
            const int kv0 = (it + 1) * 64;
            short* bK = lsK[buf ^ 1]; short* bV = lsV[buf ^ 1];
            async16(Kg + (size_t)(kv0 + rK) * 1024 + cK,      bK + t * 8);
            async16(Kg + (size_t)(kv0 + 32 + rK) * 1024 + cK, bK + t * 8 + 2048);
            async16(Vg + (size_t)(kv0 + kvV) * 1024 + dV0,    bV + t * 8);
            async16(Vg + (size_t)(kv0 + kvV) * 1024 + dV1,    bV + t * 8 + 2048);
        }
        const short* cbK = lsK[buf];
        const short* cbV = lsV[buf];

        // ---- QK^T (swapped): s[m][cb][r] = S[q=m*16+lr][kv=cb*16+kg*4+r]
        f32x4 s[2][4];
        const int x0 = ((kg)     ^ (lr & 7)) * 8;
        const int x1 = ((4 + kg) ^ (lr & 7)) * 8;
#pragma unroll
        for (int cb = 0; cb < 4; ++cb) {
            const bf16x8 kA0 = *(const bf16x8*)&cbK[(cb * 16 + lr) * 64 + x0];
            const bf16x8 kA1 = *(const bf16x8*)&cbK[(cb * 16 + lr) * 64 + x1];
#pragma unroll
            for (int m = 0; m < 2; ++m) {
                f32x4 a = __builtin_amdgcn_mfma_f32_16x16x32_bf16(kA0, qB[m][0], zero4(), 0, 0, 0);
                s[m][cb] = __builtin_amdgcn_mfma_f32_16x16x32_bf16(kA1, qB[m][1], a, 0, 0, 0);
            }
        }

        // ---- online softmax; lane owns q = m*16 + lr (raw-score max tracking)
        float corrS[2];
#pragma unroll
        for (int m = 0; m < 2; ++m) {
            float smax = fmaxf(fmaxf(s[m][0][0], s[m][0][1]), fmaxf(s[m][0][2], s[m][0][3]));
#pragma unroll
            for (int cb = 1; cb < 4; ++cb)
                smax = fmaxf(smax, fmaxf(fmaxf(s[m][cb][0], s[m][cb][1]),
                                         fmaxf(s[m][cb][2], s[m][cb][3])));
            smax = fmaxf(smax, __shfl_xor(smax, 16));
            smax = fmaxf(smax, __shfl_xor(smax, 32));
            const float mnew = fmaxf(mx[m], smax);
            corrS[m] = __expf((mx[m] - mnew) * 0.125f);
            mx[m] = mnew;
            const float nm = mnew * 0.125f;
            float tsum = 0.f;
            short* pRow = &lsP[w][(m * 16 + lr) * 72];
#pragma unroll
            for (int cb = 0; cb < 4; ++cb) {
                const float p0 = __expf(fmaf(s[m][cb][0], 0.125f, -nm));
                const float p1 = __expf(fmaf(s[m][cb][1], 0.125f, -nm));
                const float p2 = __expf(fmaf(s[m][cb][2], 0.125f, -nm));
                const float p3 = __expf(fmaf(s[m][cb][3], 0.125f, -nm));
                tsum += (p0 + p1) + (p2 + p3);
                union { float f; uint32_t u; } a0{p0}, a1{p1}, a2{p2}, a3{p3};
                // truncation-pack (bias cancels in the softmax ratio)
                const uint32_t w01 = (a0.u >> 16) | (a1.u & 0xFFFF0000u);
                const uint32_t w23 = (a2.u >> 16) | (a3.u & 0xFFFF0000u);
                *(uint32_t*)&pRow[cb * 16 + kg * 4]     = w01;
                *(uint32_t*)&pRow[cb * 16 + kg * 4 + 2] = w23;
            }
            tsum += __shfl_xor(tsum, 16);
            tsum += __shfl_xor(tsum, 32);
            lsum[m] = lsum[m] * corrS[m] + tsum;
        }

        // ---- rescale o (rows kg*4+r) with corr broadcast from softmax lanes
#pragma unroll
        for (int m = 0; m < 2; ++m) {
            f32x4 c;
#pragma unroll
            for (int r = 0; r < 4; ++r) c[r] = __shfl(corrS[m], kg * 4 + r);
#pragma unroll
            for (int n = 0; n < 4; ++n) {
                o[m][n][0] *= c[0]; o[m][n][1] *= c[1];
                o[m][n][2] *= c[2]; o[m][n][3] *= c[3];
            }
        }

        // ---- PV: O[q][d] += P[q][kv] V[kv][d]
        bf16x8 pA[2][2];
#pragma unroll
        for (int m = 0; m < 2; ++m)
#pragma unroll
            for (int kh = 0; kh < 2; ++kh)
                pA[m][kh] = *(const bf16x8*)&lsP[w][(m * 16 + lr) * 72 + kh * 32 + kg * 8];

        bf16x4 tv[4][4];
#pragma unroll
        for (int n = 0; n < 4; ++n) {
            const uint32_t a = lds_addr(&cbV[n * 1024 + kg * 128 + lr]);
            asm volatile(
                "ds_read_b64_tr_b16 %0, %4\n\t"
                "ds_read_b64_tr_b16 %1, %4 offset:128\n\t"
                "ds_read_b64_tr_b16 %2, %4 offset:1024\n\t"
                "ds_read_b64_tr_b16 %3, %4 offset:1152"
                : "=&v"(tv[n][0]), "=&v"(tv[n][1]), "=&v"(tv[n][2]), "=&v"(tv[n][3])
                : "v"(a));
        }
        asm volatile("s_waitcnt lgkmcnt(0)" ::: "memory");
        __builtin_amdgcn_sched_barrier(0);

#pragma unroll
        for (int n = 0; n < 4; ++n) {
#pragma unroll
            for (int kh = 0; kh < 2; ++kh) {
                const bf16x8 vB = __builtin_shufflevector(tv[n][kh * 2], tv[n][kh * 2 + 1],
                                                          0, 1, 2, 3, 4, 5, 6, 7);
#pragma unroll
                for (int m = 0; m < 2; ++m)
                    o[m][n] = __builtin_amdgcn_mfma_f32_16x16x32_bf16(pA[m][kh], vB, o[m][n], 0, 0, 0);
            }
        }
        buf ^= 1;
    }

    // ---- epilogue: normalize by lsum of each o-row
#pragma unroll
    for (int m = 0; m < 2; ++m) {
        f32x4 inv;
#pragma unroll
        for (int r = 0; r < 4; ++r) inv[r] = 1.0f / __shfl(lsum[m], kg * 4 + r);
#pragma unroll
        for (int n = 0; n < 4; ++n)
#pragma unroll
            for (int r = 0; r < 4; ++r) {
                const int row = q0 + m * 16 + kg * 4 + r;
                Og[(size_t)row * 1024 + n * 16 + lr] = f2b(o[m][n][r] * inv[r]);
            }
    }
}

// ---------------------------------------------------------------------------
// In-place rowwise LayerNorm on d_out (fp32) (unchanged, verified round 7).
// ---------------------------------------------------------------------------
__global__ __launch_bounds__(256)
void ln_inplace(float* __restrict__ io, const float* __restrict__ gamma,
                const float* __restrict__ beta)
{
    __shared__ float redS[4];
    __shared__ float redQ[4];
    const int t = threadIdx.x, wave = t >> 6, lane = t & 63;
    const size_t rb = (size_t)blockIdx.x * 1024;

    float4 v4 = *(const float4*)&io[rb + t * 4];
    float v[4] = {v4.x, v4.y, v4.z, v4.w};

    float s = 0.f, sq = 0.f;
#pragma unroll
    for (int j = 0; j < 4; ++j) { s += v[j]; sq += v[j] * v[j]; }
#pragma unroll
    for (int off = 32; off; off >>= 1) {
        s  += __shfl_xor(s, off);
        sq += __shfl_xor(sq, off);
    }
    if (lane == 0) { redS[wave] = s; redQ[wave] = sq; }
    __syncthreads();
    const float mean = (redS[0] + redS[1] + redS[2] + redS[3]) * (1.0f / 1024.0f);
    const float ex2  = (redQ[0] + redQ[1] + redQ[2] + redQ[3]) * (1.0f / 1024.0f);
    const float var  = fmaxf(ex2 - mean * mean, 0.f);
    const float inv  = rsqrtf(var + 1e-5f);

    float4 o4;
    o4.x = (v[0] - mean) * inv * gamma[t * 4 + 0] + beta[t * 4 + 0];
    o4.y = (v[1] - mean) * inv * gamma[t * 4 + 1] + beta[t * 4 + 1];
    o4.z = (v[2] - mean) * inv * gamma[t * 4 + 2] + beta[t * 4 + 2];
    o4.w = (v[3] - mean) * inv * gamma[t * 4 + 3] + beta[t * 4 + 3];
    *(float4*)&io[rb + t * 4] = o4;
}

// ---------------------------------------------------------------------------
extern "C" void kernel_launch(void* const* d_in, const int* in_sizes, int n_in,
                              void* d_out, int out_size, void* d_ws, size_t ws_size,
                              hipStream_t stream)
{
    const float* x  = (const float*)d_in[0];
    const float* Wq = (const float*)d_in[1];
    const float* bq = (const float*)d_in[2];
    const float* Wk = (const float*)d_in[3];
    const float* bk = (const float*)d_in[4];
    const float* Wv = (const float*)d_in[5];
    const float* bv = (const float*)d_in[6];
    const float* Wo = (const float*)d_in[7];
    const float* bo = (const float*)d_in[8];
    const float* gamma = (const float*)d_in[9];
    const float* beta  = (const float*)d_in[10];

    const size_t NX = (size_t)8192 * 1024;
    const size_t NW = (size_t)1024 * 1024;

    short* xb  = (short*)d_ws;
    short* Wqb = xb + NX;
    short* Wkb = Wqb + NW;
    short* Wvb = Wkb + NW;
    short* Wob = Wvb + NW;
    short* Qw  = Wob + NW;
    short* Kw  = Qw + NX;
    short* Vw  = Kw + NX;
    short* Cw  = Vw + NX;
    float* out = (float*)d_out;

    dim3 blk(256);
    cvt5<<<dim3(12288), blk, 0, stream>>>(x, Wq, Wk, Wv, Wo, xb, Wqb, Wkb, Wvb, Wob);
    gemm_bt<false, false><<<dim3(8, 64), blk, 0, stream>>>(xb, Wqb, bq, nullptr, Qw, 8192, 1024, 1024);
    gemm_bt<false, false><<<dim3(8, 64), blk, 0, stream>>>(xb, Wkb, bk, nullptr, Kw, 8192, 1024, 1024);
    gemm_bt<false, false><<<dim3(8, 64), blk, 0, stream>>>(xb, Wvb, bv, nullptr, Vw, 8192, 1024, 1024);
    attn_fwd<<<dim3(64, 16), blk, 0, stream>>>(Qw, Kw, Vw, Cw);
    gemm_bt<true,  true ><<<dim3(8, 64), blk, 0, stream>>>(Cw, Wob, bo, x, out, 8192, 1024, 1024);
    ln_inplace<<<dim3(8192), blk, 0, stream>>>(out, gamma, beta);
}

// Round 9
// 241.586 us; speedup vs baseline: 2.1578x; 1.2333x over previous
//
#include <hip/hip_runtime.h>
#include <hip/hip_bf16.h>
#include <stdint.h>

typedef __attribute__((ext_vector_type(4))) float f32x4;
typedef __attribute__((ext_vector_type(8))) short bf16x8;
typedef __attribute__((ext_vector_type(4))) short bf16x4;
typedef __attribute__((ext_vector_type(4))) short s16x4;

__device__ __forceinline__ float b2f(short s) {
    union { uint32_t u; float f; } v; v.u = ((uint32_t)(uint16_t)s) << 16; return v.f;
}
__device__ __forceinline__ short f2b(float f) {
    union { float f; uint32_t u; } v; v.f = f;
    uint32_t r = v.u + 0x7FFF + ((v.u >> 16) & 1);   // RNE
    return (short)(r >> 16);
}
__device__ __forceinline__ f32x4 zero4() { f32x4 z = {0.f, 0.f, 0.f, 0.f}; return z; }

__device__ __forceinline__ void async16(const void* g, void* l) {
    __builtin_amdgcn_global_load_lds(
        (const __attribute__((address_space(1))) void*)g,
        (__attribute__((address_space(3))) void*)l, 16, 0, 0);
}
__device__ __forceinline__ uint32_t lds_addr(const void* p) {
    return (uint32_t)(uintptr_t)(const __attribute__((address_space(3))) void*)p;
}
// v_exp_f32 computes 2^x natively — avoids the hidden mul in __expf
__device__ __forceinline__ float exp2fast(float x) {
    float r; asm("v_exp_f32 %0, %1" : "=v"(r) : "v"(x)); return r;
}
// packed RNE f32->bf16 pair (no builtin on gfx950)
__device__ __forceinline__ uint32_t cvtpk(float lo, float hi) {
    uint32_t r; asm("v_cvt_pk_bf16_f32 %0, %1, %2" : "=v"(r) : "v"(lo), "v"(hi)); return r;
}

// ---------------------------------------------------------------------------
// fp32 -> bf16 conversion pre-pass (unchanged, verified).
// ---------------------------------------------------------------------------
__global__ __launch_bounds__(256)
void cvt5(const float* __restrict__ x,
          const float* __restrict__ wq, const float* __restrict__ wk,
          const float* __restrict__ wv, const float* __restrict__ wo,
          short* __restrict__ xb, short* __restrict__ wqb, short* __restrict__ wkb,
          short* __restrict__ wvb, short* __restrict__ wob)
{
    const int b = blockIdx.x;
    const float* src; short* dst; size_t off;
    if (b < 8192) { src = x; dst = xb; off = (size_t)b * 1024; }
    else {
        const int wsel = (b - 8192) >> 10;
        off = (size_t)((b - 8192) & 1023) * 1024;
        switch (wsel) {
            case 0: src = wq; dst = wqb; break;
            case 1: src = wk; dst = wkb; break;
            case 2: src = wv; dst = wvb; break;
            default: src = wo; dst = wob; break;
        }
    }
    const int t = threadIdx.x;
    const float4 v = *(const float4*)(src + off + t * 4);
    s16x4 o;
    o[0] = f2b(v.x); o[1] = f2b(v.y); o[2] = f2b(v.z); o[3] = f2b(v.w);
    *(s16x4*)(dst + off + t * 4) = o;
}

// ---------------------------------------------------------------------------
// Fused QKV GEMM: one dispatch, grid (24, 64).  Weight rows are the
// CONTIGUOUS ws concat [Wq;Wk;Wv] (3072 x 1024).  Block n-index selects
// output tensor (0-7 -> Q, 8-15 -> K, 16-23 -> V) and bias pointer.
// Core identical to verified gemm_bt.
// ---------------------------------------------------------------------------
__global__ __launch_bounds__(256)
void gemm_qkv(const short* __restrict__ A, const short* __restrict__ Wcat,
              const float* __restrict__ bq, const float* __restrict__ bk,
              const float* __restrict__ bv,
              short* __restrict__ Qw, short* __restrict__ Kw, short* __restrict__ Vw)
{
    __shared__ short lsA[128 * 32];
    __shared__ short lsB[128 * 32];
    const int K = 1024;
    const int t = threadIdx.x;
    const int wave = t >> 6, lane = t & 63;
    const int wr = wave >> 1, wc = wave & 1;
    const int lr = lane & 15, kg = lane >> 4;
    const int m0 = blockIdx.y * 128;
    const int nb = blockIdx.x;
    const int tb = nb >> 3;                        // 0=Q 1=K 2=V
    const int n0c = (nb & 7) * 128;                // col within tensor
    const float* bias = (tb == 0) ? bq : (tb == 1) ? bk : bv;
    short* dst = (tb == 0) ? Qw : (tb == 1) ? Kw : Vw;

    f32x4 acc[4][4];
#pragma unroll
    for (int m = 0; m < 4; ++m)
#pragma unroll
        for (int n = 0; n < 4; ++n) acc[m][n] = zero4();

    const short* Ab = A + (size_t)m0 * K;
    const short* Bb = Wcat + (size_t)nb * 128 * K;
    const int r0 = t >> 2;
    const int c0 = (t & 3) * 8;

    for (int k0 = 0; k0 < K; k0 += 32) {
        __syncthreads();
        async16(Ab + (size_t)r0 * K + k0 + c0,        &lsA[t * 8]);
        async16(Ab + (size_t)(r0 + 64) * K + k0 + c0, &lsA[t * 8 + 2048]);
        async16(Bb + (size_t)r0 * K + k0 + c0,        &lsB[t * 8]);
        async16(Bb + (size_t)(r0 + 64) * K + k0 + c0, &lsB[t * 8 + 2048]);
        __syncthreads();

        bf16x8 aF[4], bF[4];
#pragma unroll
        for (int m = 0; m < 4; ++m)
            aF[m] = *(const bf16x8*)&lsA[(wr * 64 + m * 16 + lr) * 32 + kg * 8];
#pragma unroll
        for (int n = 0; n < 4; ++n)
            bF[n] = *(const bf16x8*)&lsB[(wc * 64 + n * 16 + lr) * 32 + kg * 8];
#pragma unroll
        for (int m = 0; m < 4; ++m)
#pragma unroll
            for (int n = 0; n < 4; ++n)
                acc[m][n] = __builtin_amdgcn_mfma_f32_16x16x32_bf16(aF[m], bF[n], acc[m][n], 0, 0, 0);
    }

#pragma unroll
    for (int n = 0; n < 4; ++n) {
        const int col = n0c + wc * 64 + n * 16 + lr;
        const float bvv = bias[col];
#pragma unroll
        for (int m = 0; m < 4; ++m) {
            const int rowb = m0 + wr * 64 + m * 16 + kg * 4;
#pragma unroll
            for (int r = 0; r < 4; ++r)
                dst[(size_t)(rowb + r) * 1024 + col] = f2b(acc[m][n][r] + bvv);
        }
    }
}

// ---------------------------------------------------------------------------
// Out-projection GEMM (unchanged, verified): fp32 C + residual.
// ---------------------------------------------------------------------------
__global__ __launch_bounds__(256)
void gemm_out(const short* __restrict__ A, const short* __restrict__ Bw,
              const float* __restrict__ bias, const float* __restrict__ resid,
              float* __restrict__ C)
{
    __shared__ short lsA[128 * 32];
    __shared__ short lsB[128 * 32];
    const int K = 1024, N = 1024;
    const int t = threadIdx.x;
    const int wave = t >> 6, lane = t & 63;
    const int wr = wave >> 1, wc = wave & 1;
    const int lr = lane & 15, kg = lane >> 4;
    const int m0 = blockIdx.y * 128;
    const int n0 = blockIdx.x * 128;

    f32x4 acc[4][4];
#pragma unroll
    for (int m = 0; m < 4; ++m)
#pragma unroll
        for (int n = 0; n < 4; ++n) acc[m][n] = zero4();

    const short* Ab = A + (size_t)m0 * K;
    const short* Bb = Bw + (size_t)n0 * K;
    const int r0 = t >> 2;
    const int c0 = (t & 3) * 8;

    for (int k0 = 0; k0 < K; k0 += 32) {
        __syncthreads();
        async16(Ab + (size_t)r0 * K + k0 + c0,        &lsA[t * 8]);
        async16(Ab + (size_t)(r0 + 64) * K + k0 + c0, &lsA[t * 8 + 2048]);
        async16(Bb + (size_t)r0 * K + k0 + c0,        &lsB[t * 8]);
        async16(Bb + (size_t)(r0 + 64) * K + k0 + c0, &lsB[t * 8 + 2048]);
        __syncthreads();

        bf16x8 aF[4], bF[4];
#pragma unroll
        for (int m = 0; m < 4; ++m)
            aF[m] = *(const bf16x8*)&lsA[(wr * 64 + m * 16 + lr) * 32 + kg * 8];
#pragma unroll
        for (int n = 0; n < 4; ++n)
            bF[n] = *(const bf16x8*)&lsB[(wc * 64 + n * 16 + lr) * 32 + kg * 8];
#pragma unroll
        for (int m = 0; m < 4; ++m)
#pragma unroll
            for (int n = 0; n < 4; ++n)
                acc[m][n] = __builtin_amdgcn_mfma_f32_16x16x32_bf16(aF[m], bF[n], acc[m][n], 0, 0, 0);
    }

#pragma unroll
    for (int n = 0; n < 4; ++n) {
        const int col = n0 + wc * 64 + n * 16 + lr;
        const float bvv = bias[col];
#pragma unroll
        for (int m = 0; m < 4; ++m) {
            const int rowb = m0 + wr * 64 + m * 16 + kg * 4;
#pragma unroll
            for (int r = 0; r < 4; ++r) {
                const size_t idx = (size_t)(rowb + r) * N + col;
                C[idx] = acc[m][n][r] + bvv + resid[idx];
            }
        }
    }
}

// ---------------------------------------------------------------------------
// MFMA flash attention v3: v2 + exp2-domain softmax (folded scale),
// cvt_pk P-pack (RNE), defer-max rescale (THR = 64 raw = 8 nat units),
// s_setprio around MFMA clusters.
// ---------------------------------------------------------------------------
__global__ __launch_bounds__(256)
void attn_fwd(const short* __restrict__ Q, const short* __restrict__ K,
              const short* __restrict__ V, short* __restrict__ ctx)
{
    __shared__ short lsK[2][64 * 64];
    __shared__ short lsV[2][64 * 64];
    __shared__ short lsP[4][32 * 72];

    const float C1 = 0.18033688011112042f;   // 0.125 * log2(e)

    const int t = threadIdx.x, w = t >> 6, lane = t & 63;
    const int lr = lane & 15, kg = lane >> 4;
    const int bh = blockIdx.x;
    const size_t base = (size_t)(bh >> 4) * 2048 * 1024 + (size_t)(bh & 15) * 64;
    const short* Qg = Q + base;
    const short* Kg = K + base;
    const short* Vg = V + base;
    short* Og = ctx + base;
    const int q0 = blockIdx.y * 128 + w * 32;

    bf16x8 qB[2][2];
#pragma unroll
    for (int m = 0; m < 2; ++m)
#pragma unroll
        for (int ks = 0; ks < 2; ++ks)
            qB[m][ks] = *(const bf16x8*)(Qg + (size_t)(q0 + m * 16 + lr) * 1024 + ks * 32 + kg * 8);

    const int rK  = t >> 3;
    const int cK  = (((t & 7) ^ (rK & 7))) * 8;
    const int kvV = (t & 127) >> 1;
    const int dV0 = ((t >> 7) << 4) + (t & 1) * 8;
    const int dV1 = dV0 + 32;

    f32x4 o[2][4];
#pragma unroll
    for (int m = 0; m < 2; ++m)
#pragma unroll
        for (int n = 0; n < 4; ++n) o[m][n] = zero4();
    float mx[2] = {-1e30f, -1e30f};
    float lsum[2] = {0.f, 0.f};

    async16(Kg + (size_t)rK * 1024 + cK,        &lsK[0][t * 8]);
    async16(Kg + (size_t)(32 + rK) * 1024 + cK, &lsK[0][t * 8 + 2048]);
    async16(Vg + (size_t)kvV * 1024 + dV0,      &lsV[0][t * 8]);
    async16(Vg + (size_t)kvV * 1024 + dV1,      &lsV[0][t * 8 + 2048]);

    int buf = 0;
    for (int it = 0; it < 32; ++it) {
        __syncthreads();
        if (it + 1 < 32) {
            const int kv0 = (it + 1) * 64;
            short* bK = lsK[buf ^ 1]; short* bV = lsV[buf ^ 1];
            async16(Kg + (size_t)(kv0 + rK) * 1024 + cK,      bK + t * 8);
            async16(Kg + (size_t)(kv0 + 32 + rK) * 1024 + cK, bK + t * 8 + 2048);
            async16(Vg + (size_t)(kv0 + kvV) * 1024 + dV0,    bV + t * 8);
            async16(Vg + (size_t)(kv0 + kvV) * 1024 + dV1,    bV + t * 8 + 2048);
        }
        const short* cbK = lsK[buf];
        const short* cbV = lsV[buf];

        // ---- QK^T (swapped): lane owns q-row m*16+lr
        f32x4 s[2][4];
        const int x0 = ((kg)     ^ (lr & 7)) * 8;
        const int x1 = ((4 + kg) ^ (lr & 7)) * 8;
        __builtin_amdgcn_s_setprio(1);
#pragma unroll
        for (int cb = 0; cb < 4; ++cb) {
            const bf16x8 kA0 = *(const bf16x8*)&cbK[(cb * 16 + lr) * 64 + x0];
            const bf16x8 kA1 = *(const bf16x8*)&cbK[(cb * 16 + lr) * 64 + x1];
#pragma unroll
            for (int m = 0; m < 2; ++m) {
                f32x4 a = __builtin_amdgcn_mfma_f32_16x16x32_bf16(kA0, qB[m][0], zero4(), 0, 0, 0);
                s[m][cb] = __builtin_amdgcn_mfma_f32_16x16x32_bf16(kA1, qB[m][1], a, 0, 0, 0);
            }
        }
        __builtin_amdgcn_s_setprio(0);

        // ---- tile max per q-row (in-lane tree + 2 shfl)
        float smax[2];
#pragma unroll
        for (int m = 0; m < 2; ++m) {
            float a = fmaxf(fmaxf(s[m][0][0], s[m][0][1]), fmaxf(s[m][0][2], s[m][0][3]));
            float b = fmaxf(fmaxf(s[m][1][0], s[m][1][1]), fmaxf(s[m][1][2], s[m][1][3]));
            float c = fmaxf(fmaxf(s[m][2][0], s[m][2][1]), fmaxf(s[m][2][2], s[m][2][3]));
            float d = fmaxf(fmaxf(s[m][3][0], s[m][3][1]), fmaxf(s[m][3][2], s[m][3][3]));
            float e = fmaxf(fmaxf(a, b), fmaxf(c, d));
            e = fmaxf(e, __shfl_xor(e, 16));
            e = fmaxf(e, __shfl_xor(e, 32));
            smax[m] = e;
        }

        // ---- defer-max: rescale only when some row grew past THR (raw 64)
        if (!__all((smax[0] <= mx[0] + 64.f) && (smax[1] <= mx[1] + 64.f))) {
            float corrS[2];
#pragma unroll
            for (int m = 0; m < 2; ++m) {
                const float mnew = fmaxf(mx[m], smax[m]);
                corrS[m] = exp2fast((mx[m] - mnew) * C1);
                mx[m] = mnew;
                lsum[m] *= corrS[m];
            }
#pragma unroll
            for (int m = 0; m < 2; ++m) {
                f32x4 c;
#pragma unroll
                for (int r = 0; r < 4; ++r) c[r] = __shfl(corrS[m], kg * 4 + r);
#pragma unroll
                for (int n = 0; n < 4; ++n) {
                    o[m][n][0] *= c[0]; o[m][n][1] *= c[1];
                    o[m][n][2] *= c[2]; o[m][n][3] *= c[3];
                }
            }
        }

        // ---- P = 2^(s*C1 - mx*C1), pack RNE bf16 pairs, row-sum
#pragma unroll
        for (int m = 0; m < 2; ++m) {
            const float nm2 = mx[m] * C1;
            float tsum = 0.f;
            short* pRow = &lsP[w][(m * 16 + lr) * 72];
#pragma unroll
            for (int cb = 0; cb < 4; ++cb) {
                const float p0 = exp2fast(fmaf(s[m][cb][0], C1, -nm2));
                const float p1 = exp2fast(fmaf(s[m][cb][1], C1, -nm2));
                const float p2 = exp2fast(fmaf(s[m][cb][2], C1, -nm2));
                const float p3 = exp2fast(fmaf(s[m][cb][3], C1, -nm2));
                tsum += (p0 + p1) + (p2 + p3);
                *(uint32_t*)&pRow[cb * 16 + kg * 4]     = cvtpk(p0, p1);
                *(uint32_t*)&pRow[cb * 16 + kg * 4 + 2] = cvtpk(p2, p3);
            }
            tsum += __shfl_xor(tsum, 16);
            tsum += __shfl_xor(tsum, 32);
            lsum[m] += tsum;
        }

        // ---- PV
        bf16x8 pA[2][2];
#pragma unroll
        for (int m = 0; m < 2; ++m)
#pragma unroll
            for (int kh = 0; kh < 2; ++kh)
                pA[m][kh] = *(const bf16x8*)&lsP[w][(m * 16 + lr) * 72 + kh * 32 + kg * 8];

        bf16x4 tv[4][4];
#pragma unroll
        for (int n = 0; n < 4; ++n) {
            const uint32_t a = lds_addr(&cbV[n * 1024 + kg * 128 + lr]);
            asm volatile(
                "ds_read_b64_tr_b16 %0, %4\n\t"
                "ds_read_b64_tr_b16 %1, %4 offset:128\n\t"
                "ds_read_b64_tr_b16 %2, %4 offset:1024\n\t"
                "ds_read_b64_tr_b16 %3, %4 offset:1152"
                : "=&v"(tv[n][0]), "=&v"(tv[n][1]), "=&v"(tv[n][2]), "=&v"(tv[n][3])
                : "v"(a));
        }
        asm volatile("s_waitcnt lgkmcnt(0)" ::: "memory");
        __builtin_amdgcn_sched_barrier(0);

        __builtin_amdgcn_s_setprio(1);
#pragma unroll
        for (int n = 0; n < 4; ++n) {
#pragma unroll
            for (int kh = 0; kh < 2; ++kh) {
                const bf16x8 vB = __builtin_shufflevector(tv[n][kh * 2], tv[n][kh * 2 + 1],
                                                          0, 1, 2, 3, 4, 5, 6, 7);
#pragma unroll
                for (int m = 0; m < 2; ++m)
                    o[m][n] = __builtin_amdgcn_mfma_f32_16x16x32_bf16(pA[m][kh], vB, o[m][n], 0, 0, 0);
            }
        }
        __builtin_amdgcn_s_setprio(0);
        buf ^= 1;
    }

#pragma unroll
    for (int m = 0; m < 2; ++m) {
        f32x4 inv;
#pragma unroll
        for (int r = 0; r < 4; ++r) inv[r] = 1.0f / __shfl(lsum[m], kg * 4 + r);
#pragma unroll
        for (int n = 0; n < 4; ++n)
#pragma unroll
            for (int r = 0; r < 4; ++r) {
                const int row = q0 + m * 16 + kg * 4 + r;
                Og[(size_t)row * 1024 + n * 16 + lr] = f2b(o[m][n][r] * inv[r]);
            }
    }
}

// ---------------------------------------------------------------------------
// In-place rowwise LayerNorm on d_out (fp32) (unchanged, verified).
// ---------------------------------------------------------------------------
__global__ __launch_bounds__(256)
void ln_inplace(float* __restrict__ io, const float* __restrict__ gamma,
                const float* __restrict__ beta)
{
    __shared__ float redS[4];
    __shared__ float redQ[4];
    const int t = threadIdx.x, wave = t >> 6, lane = t & 63;
    const size_t rb = (size_t)blockIdx.x * 1024;

    float4 v4 = *(const float4*)&io[rb + t * 4];
    float v[4] = {v4.x, v4.y, v4.z, v4.w};

    float s = 0.f, sq = 0.f;
#pragma unroll
    for (int j = 0; j < 4; ++j) { s += v[j]; sq += v[j] * v[j]; }
#pragma unroll
    for (int off = 32; off; off >>= 1) {
        s  += __shfl_xor(s, off);
        sq += __shfl_xor(sq, off);
    }
    if (lane == 0) { redS[wave] = s; redQ[wave] = sq; }
    __syncthreads();
    const float mean = (redS[0] + redS[1] + redS[2] + redS[3]) * (1.0f / 1024.0f);
    const float ex2  = (redQ[0] + redQ[1] + redQ[2] + redQ[3]) * (1.0f / 1024.0f);
    const float var  = fmaxf(ex2 - mean * mean, 0.f);
    const float inv  = rsqrtf(var + 1e-5f);

    float4 o4;
    o4.x = (v[0] - mean) * inv * gamma[t * 4 + 0] + beta[t * 4 + 0];
    o4.y = (v[1] - mean) * inv * gamma[t * 4 + 1] + beta[t * 4 + 1];
    o4.z = (v[2] - mean) * inv * gamma[t * 4 + 2] + beta[t * 4 + 2];
    o4.w = (v[3] - mean) * inv * gamma[t * 4 + 3] + beta[t * 4 + 3];
    *(float4*)&io[rb + t * 4] = o4;
}

// ---------------------------------------------------------------------------
extern "C" void kernel_launch(void* const* d_in, const int* in_sizes, int n_in,
                              void* d_out, int out_size, void* d_ws, size_t ws_size,
                              hipStream_t stream)
{
    const float* x  = (const float*)d_in[0];
    const float* Wq = (const float*)d_in[1];
    const float* bq = (const float*)d_in[2];
    const float* Wk = (const float*)d_in[3];
    const float* bk = (const float*)d_in[4];
    const float* Wv = (const float*)d_in[5];
    const float* bv = (const float*)d_in[6];
    const float* Wo = (const float*)d_in[7];
    const float* bo = (const float*)d_in[8];
    const float* gamma = (const float*)d_in[9];
    const float* beta  = (const float*)d_in[10];

    const size_t NX = (size_t)8192 * 1024;
    const size_t NW = (size_t)1024 * 1024;

    short* xb  = (short*)d_ws;
    short* Wqb = xb + NX;          // [Wq;Wk;Wv] contiguous for fused GEMM
    short* Wkb = Wqb + NW;
    short* Wvb = Wkb + NW;
    short* Wob = Wvb + NW;
    short* Qw  = Wob + NW;
    short* Kw  = Qw + NX;
    short* Vw  = Kw + NX;
    short* Cw  = Vw + NX;
    float* out = (float*)d_out;

    dim3 blk(256);
    cvt5<<<dim3(12288), blk, 0, stream>>>(x, Wq, Wk, Wv, Wo, xb, Wqb, Wkb, Wvb, Wob);
    gemm_qkv<<<dim3(24, 64), blk, 0, stream>>>(xb, Wqb, bq, bk, bv, Qw, Kw, Vw);
    attn_fwd<<<dim3(64, 16), blk, 0, stream>>>(Qw, Kw, Vw, Cw);
    gemm_out<<<dim3(8, 64), blk, 0, stream>>>(Cw, Wob, bo, x, out);
    ln_inplace<<<dim3(8192), blk, 0, stream>>>(out, gamma, beta);
}